// Round 1
// baseline (5716.389 us; speedup 1.0000x reference)
//
#include <hip/hip_runtime.h>
#include <hip/hip_bf16.h>
#include <hip/hip_cooperative_groups.h>

#define V  32000
#define HD 512
#define BB 32
#define TT 128
#define VH 32512   // V + HD

typedef short  short8  __attribute__((ext_vector_type(8)));
typedef unsigned short ushort8 __attribute__((ext_vector_type(8)));
typedef float  f32x4   __attribute__((ext_vector_type(4)));

__device__ __forceinline__ unsigned short bf16_rne(float f) {
  unsigned u = __builtin_bit_cast(unsigned, f);
  u += 0x7FFFu + ((u >> 16) & 1u);
  return (unsigned short)(u >> 16);
}

__device__ __forceinline__ void gload_lds16(const void* g, void* l) {
  __builtin_amdgcn_global_load_lds((const __attribute__((address_space(1))) void*)g,
                                   (__attribute__((address_space(3))) void*)l, 16, 0, 0);
}

// ---------------------------------------------------------------------------
// Phase A: embedding gather. E[t][g][b][q] = W_g[q][x_tb] + bias_g[q]
// block = (t,b); threads sweep (g,q) with coalesced writes across q.
// ---------------------------------------------------------------------------
__global__ void __launch_bounds__(256) gather_kernel(
    float* __restrict__ E, const int* __restrict__ X,
    const float* __restrict__ Wf, const float* __restrict__ bf,
    const float* __restrict__ Wi, const float* __restrict__ bi,
    const float* __restrict__ Wo, const float* __restrict__ bo,
    const float* __restrict__ Wc, const float* __restrict__ bc)
{
  const int bid = blockIdx.x;
  const int t = bid >> 5, b = bid & 31;
  const int x = X[b * TT + t];
  const int tid = threadIdx.x;
  #pragma unroll
  for (int i = 0; i < 8; ++i) {
    const int g = i >> 1;
    const int q = ((i & 1) << 8) + tid;
    const float* W = (g == 0) ? Wf : (g == 1) ? Wi : (g == 2) ? Wo : Wc;
    const float* bs = (g == 0) ? bf : (g == 1) ? bi : (g == 2) ? bo : bc;
    const float e = W[(size_t)q * VH + x] + bs[q];
    E[(((size_t)t * 4 + g) * 32 + b) * 512 + q] = e;
  }
}

// ---------------------------------------------------------------------------
// f32 -> bf16 bulk convert (for Wy)
// ---------------------------------------------------------------------------
__global__ void __launch_bounds__(256) f32_to_bf16_k(
    unsigned short* __restrict__ dst, const float* __restrict__ src, size_t n)
{
  const size_t i = ((size_t)blockIdx.x * 256 + threadIdx.x) * 8;
  if (i >= n) return;
  const float4 a = *(const float4*)(src + i);
  const float4 b = *(const float4*)(src + i + 4);
  ushort8 o;
  o[0] = bf16_rne(a.x); o[1] = bf16_rne(a.y); o[2] = bf16_rne(a.z); o[3] = bf16_rne(a.w);
  o[4] = bf16_rne(b.x); o[5] = bf16_rne(b.y); o[6] = bf16_rne(b.z); o[7] = bf16_rne(b.w);
  *(ushort8*)(dst + i) = o;
}

// ---------------------------------------------------------------------------
// Phase B: LSTM recurrence. Cooperative kernel, 256 blocks x 256 threads.
// Block owns q0=2*bid, q0+1 for ALL steps (c lives in LDS the whole kernel).
// Thread (kc = tid>>6, qi = (tid>>5)&1, b = tid&31): partial dot over the
// kc-th quarter of k for all 4 gates of (q0+qi, b). LDS reduce, elementwise
// update by 64 threads, h exchanged via global ping-pong + grid.sync().
// ---------------------------------------------------------------------------
__global__ void __launch_bounds__(256, 1) lstm_coop(
    const float* __restrict__ E,
    const float* __restrict__ Wf, const float* __restrict__ Wi,
    const float* __restrict__ Wo, const float* __restrict__ Wc,
    const float* __restrict__ Cin,
    float* __restrict__ h0, float* __restrict__ h1,
    unsigned short* __restrict__ Hs,
    float* __restrict__ outHC)
{
  cooperative_groups::grid_group grid = cooperative_groups::this_grid();
  __shared__ float Pp[4][4][2][32];   // [kc][gate][qi][b]
  __shared__ float c_lds[2][32];
  const int bid = blockIdx.x;
  const int tid = threadIdx.x;
  const int kc  = tid >> 6;
  const int lane = tid & 63;
  const int qi = lane >> 5;
  const int b  = lane & 31;
  const int q0 = bid * 2;
  const int q  = q0 + qi;

  const float* w0p = Wf + (size_t)q * VH + V + kc * 128;
  const float* w1p = Wi + (size_t)q * VH + V + kc * 128;
  const float* w2p = Wo + (size_t)q * VH + V + kc * 128;
  const float* w3p = Wc + (size_t)q * VH + V + kc * 128;

  // reduce-role mapping (numerically same bits, different meaning)
  const int rg = tid >> 6, rqi = (tid >> 5) & 1, rb = tid & 31;
  const int rq = q0 + rqi;

  if (tid < 64) c_lds[qi][b] = Cin[b * HD + q];
  __syncthreads();

  for (int t = 0; t < TT; ++t) {
    const float* h  = (t & 1) ? h1 : h0;
    float*       hn = (t & 1) ? h0 : h1;
    // prefetch E for this step's reduce phase (hides under the dots)
    const float e = E[(((size_t)t * 4 + rg) * 32 + rb) * 512 + rq];

    const float* hb = h + b * HD + kc * 128;
    float a0 = 0.f, a1 = 0.f, a2 = 0.f, a3 = 0.f;
    #pragma unroll 8
    for (int kk = 0; kk < 128; kk += 4) {
      const float4 h4 = *(const float4*)(hb + kk);
      const float4 w0 = *(const float4*)(w0p + kk);
      const float4 w1 = *(const float4*)(w1p + kk);
      const float4 w2 = *(const float4*)(w2p + kk);
      const float4 w3 = *(const float4*)(w3p + kk);
      a0 += h4.x*w0.x + h4.y*w0.y + h4.z*w0.z + h4.w*w0.w;
      a1 += h4.x*w1.x + h4.y*w1.y + h4.z*w1.z + h4.w*w1.w;
      a2 += h4.x*w2.x + h4.y*w2.y + h4.z*w2.z + h4.w*w2.w;
      a3 += h4.x*w3.x + h4.y*w3.y + h4.z*w3.z + h4.w*w3.w;
    }
    Pp[kc][0][qi][b] = a0;
    Pp[kc][1][qi][b] = a1;
    Pp[kc][2][qi][b] = a2;
    Pp[kc][3][qi][b] = a3;
    __syncthreads();
    {
      const float P = Pp[0][rg][rqi][rb] + Pp[1][rg][rqi][rb]
                    + Pp[2][rg][rqi][rb] + Pp[3][rg][rqi][rb] + e;
      Pp[0][rg][rqi][rb] = P;   // own slot: safe without barrier
    }
    __syncthreads();
    if (tid < 64) {
      const float pf = Pp[0][0][qi][b];
      const float pi = Pp[0][1][qi][b];
      const float po = Pp[0][2][qi][b];
      const float pc = Pp[0][3][qi][b];
      const float fg = 1.f / (1.f + expf(-pf));
      const float ig = 1.f / (1.f + expf(-pi));
      const float og = 1.f / (1.f + expf(-po));
      const float ct = tanhf(pc);
      const float cn = fg * c_lds[qi][b] + ig * ct;
      const float hv = og * tanhf(cn);
      c_lds[qi][b] = cn;
      hn[b * HD + q] = hv;
      Hs[((size_t)t * 32 + b) * 512 + q] = bf16_rne(hv);
      if (t == TT - 1) {
        outHC[b * HD + q] = hv;            // final H
        outHC[BB * HD + b * HD + q] = cn;  // final C
      }
    }
    grid.sync();
  }
}

// ---------------------------------------------------------------------------
// Phase C: Y[4096][32000] = Hs(bf16) @ Wy(bf16)^T + by.  128x128 tile, BK=64,
// 4 waves (64x64 each, 4x4 frags of 16x16x32 bf16 MFMA), global_load_lds w=16
// with XOR-swizzled LDS via pre-swizzled global source (T2 pattern, m173).
// ---------------------------------------------------------------------------
__global__ void __launch_bounds__(256, 1) gemm_kernel(
    const unsigned short* __restrict__ A,    // [4096][512]
    const unsigned short* __restrict__ Bw,   // [32000][512]
    const float* __restrict__ by,
    float* __restrict__ Y)
{
  __shared__ unsigned short As[128 * 64];
  __shared__ unsigned short Bs[128 * 64];
  const int tid = threadIdx.x;
  const int bidx = blockIdx.x;
  const int bm = bidx & 31, bn = bidx >> 5;
  const int row0 = bm << 7, col0 = bn << 7;
  const int wave = tid >> 6, lane = tid & 63;
  const int wr = wave >> 1, wc = wave & 1;
  const int fr = lane & 15;   // row (A) / col (B,C) within 16
  const int ko = lane >> 4;   // k-group of 8

  f32x4 acc[4][4];
  #pragma unroll
  for (int m = 0; m < 4; ++m)
    #pragma unroll
    for (int n = 0; n < 4; ++n)
      acc[m][n] = (f32x4){0.f, 0.f, 0.f, 0.f};

  for (int kt = 0; kt < 8; ++kt) {
    const int k0 = kt << 6;
    #pragma unroll
    for (int is = 0; is < 4; ++is) {
      const int id = is * 256 + tid;
      const int r = id >> 3;
      const int c = (id & 7) ^ (r & 7);               // pre-swizzled source chunk
      gload_lds16(A + (size_t)(row0 + r) * 512 + k0 + c * 8,
                  &As[(is * 256 + (tid & ~63)) * 8]); // wave-uniform LDS base
    }
    #pragma unroll
    for (int is = 0; is < 4; ++is) {
      const int id = is * 256 + tid;
      const int r = id >> 3;
      const int c = (id & 7) ^ (r & 7);
      gload_lds16(Bw + (size_t)(col0 + r) * 512 + k0 + c * 8,
                  &Bs[(is * 256 + (tid & ~63)) * 8]);
    }
    __syncthreads();   // compiler emits vmcnt(0) drain before barrier
    #pragma unroll
    for (int kk = 0; kk < 2; ++kk) {
      short8 af[4], bfrag[4];
      #pragma unroll
      for (int m = 0; m < 4; ++m) {
        const int r = (wr << 6) + (m << 4) + fr;
        const int c = ((kk << 2) | ko) ^ (r & 7);
        af[m] = *(const short8*)&As[r * 64 + c * 8];
      }
      #pragma unroll
      for (int n = 0; n < 4; ++n) {
        const int r = (wc << 6) + (n << 4) + fr;
        const int c = ((kk << 2) | ko) ^ (r & 7);
        bfrag[n] = *(const short8*)&Bs[r * 64 + c * 8];
      }
      #pragma unroll
      for (int m = 0; m < 4; ++m)
        #pragma unroll
        for (int n = 0; n < 4; ++n)
          acc[m][n] = __builtin_amdgcn_mfma_f32_16x16x32_bf16(
              af[m], bfrag[n], acc[m][n], 0, 0, 0);
    }
    __syncthreads();
  }

  // epilogue: C/D layout col = lane&15, row = (lane>>4)*4 + reg
  const int rgrp = lane >> 4;
  #pragma unroll
  for (int n = 0; n < 4; ++n) {
    const int col = col0 + (wc << 6) + (n << 4) + fr;
    const float bias = by[col];
    #pragma unroll
    for (int m = 0; m < 4; ++m) {
      const int rowb = row0 + (wr << 6) + (m << 4) + (rgrp << 2);
      #pragma unroll
      for (int j = 0; j < 4; ++j) {
        Y[(size_t)(rowb + j) * V + col] = acc[m][n][j] + bias;
      }
    }
  }
}

// ---------------------------------------------------------------------------
extern "C" void kernel_launch(void* const* d_in, const int* in_sizes, int n_in,
                              void* d_out, int out_size, void* d_ws, size_t ws_size,
                              hipStream_t stream)
{
  const int*   X  = (const int*)  d_in[0];
  const float* H  = (const float*)d_in[1];
  const float* C  = (const float*)d_in[2];
  const float* Wf = (const float*)d_in[3];
  const float* bf = (const float*)d_in[4];
  const float* Wi = (const float*)d_in[5];
  const float* bi = (const float*)d_in[6];
  const float* Wo = (const float*)d_in[7];
  const float* bo = (const float*)d_in[8];
  const float* Wc = (const float*)d_in[9];
  const float* bc = (const float*)d_in[10];
  const float* Wy = (const float*)d_in[11];
  const float* by = (const float*)d_in[12];

  float* Y = (float*)d_out;
  float* outHC = Y + (size_t)TT * BB * V;

  char* ws = (char*)d_ws;
  float* E             = (float*)ws;                              // 33,554,432 B
  unsigned short* Wyb  = (unsigned short*)(ws + 33554432);        // 32,768,000 B
  unsigned short* Hs   = (unsigned short*)(ws + 33554432 + 32768000); // 4,194,304 B
  float* h0            = (float*)(ws + 33554432 + 32768000 + 4194304);
  float* h1            = h0 + BB * HD;

  hipMemcpyAsync(h0, H, (size_t)BB * HD * sizeof(float),
                 hipMemcpyDeviceToDevice, stream);

  gather_kernel<<<TT * BB, 256, 0, stream>>>(E, X, Wf, bf, Wi, bi, Wo, bo, Wc, bc);
  f32_to_bf16_k<<<8000, 256, 0, stream>>>(Wyb, Wy, (size_t)V * HD);

  {
    const float* E_p = E;
    void* args[] = {(void*)&E_p, (void*)&Wf, (void*)&Wi, (void*)&Wo, (void*)&Wc,
                    (void*)&C, (void*)&h0, (void*)&h1, (void*)&Hs, (void*)&outHC};
    hipLaunchCooperativeKernel((void*)lstm_coop, dim3(256), dim3(256), args, 0, stream);
  }

  gemm_kernel<<<8000, 256, 0, stream>>>(Hs, Wyb, by, Y);
}

// Round 3
// 1175.574 us; speedup vs baseline: 4.8626x; 4.8626x over previous
//
#include <hip/hip_runtime.h>
#include <hip/hip_bf16.h>

#define V  32000
#define HD 512
#define BB 32
#define TT 128
#define VH 32512   // V + HD
#define LBLK 8     // lstm blocks (weights live in these 8 CUs' registers)

typedef short  short8  __attribute__((ext_vector_type(8)));
typedef unsigned short u16x8 __attribute__((ext_vector_type(8)));
typedef unsigned short u16x4 __attribute__((ext_vector_type(4)));
typedef float  f32x4   __attribute__((ext_vector_type(4)));

__device__ __forceinline__ unsigned short bf16_rne(float f) {
  unsigned u = __builtin_bit_cast(unsigned, f);
  u += 0x7FFFu + ((u >> 16) & 1u);
  return (unsigned short)(u >> 16);
}

__device__ __forceinline__ void gload_lds16(const void* g, void* l) {
  __builtin_amdgcn_global_load_lds((const __attribute__((address_space(1))) void*)g,
                                   (__attribute__((address_space(3))) void*)l, 16, 0, 0);
}

__device__ __forceinline__ float sigf(float x) {
  return 1.0f / (1.0f + __expf(-x));
}
__device__ __forceinline__ float tanhf_fast(float x) {
  return 1.0f - 2.0f / (1.0f + __expf(2.0f * x));  // saturates cleanly at +-1
}

// ---------------------------------------------------------------------------
// Phase A: embedding gather. E[t][g][b][q] = W_g[q][x_tb] + bias_g[q]
// ---------------------------------------------------------------------------
__global__ void __launch_bounds__(256) gather_kernel(
    float* __restrict__ E, const int* __restrict__ X,
    const float* __restrict__ Wf, const float* __restrict__ bf,
    const float* __restrict__ Wi, const float* __restrict__ bi,
    const float* __restrict__ Wo, const float* __restrict__ bo,
    const float* __restrict__ Wc, const float* __restrict__ bc)
{
  const int bid = blockIdx.x;
  const int t = bid >> 5, b = bid & 31;
  const int x = X[b * TT + t];
  const int tid = threadIdx.x;
  #pragma unroll
  for (int i = 0; i < 8; ++i) {
    const int g = i >> 1;
    const int q = ((i & 1) << 8) + tid;
    const float* W = (g == 0) ? Wf : (g == 1) ? Wi : (g == 2) ? Wo : Wc;
    const float* bs = (g == 0) ? bf : (g == 1) ? bi : (g == 2) ? bo : bc;
    const float e = W[(size_t)q * VH + x] + bs[q];
    E[(((size_t)t * 4 + g) * 32 + b) * 512 + q] = e;
  }
}

// ---------------------------------------------------------------------------
// f32 -> bf16 bulk convert
// ---------------------------------------------------------------------------
__global__ void __launch_bounds__(256) f32_to_bf16_k(
    unsigned short* __restrict__ dst, const float* __restrict__ src, size_t n)
{
  const size_t i = ((size_t)blockIdx.x * 256 + threadIdx.x) * 8;
  if (i >= n) return;
  const float4 a = *(const float4*)(src + i);
  const float4 b = *(const float4*)(src + i + 4);
  u16x8 o;
  o[0] = bf16_rne(a.x); o[1] = bf16_rne(a.y); o[2] = bf16_rne(a.z); o[3] = bf16_rne(a.w);
  o[4] = bf16_rne(b.x); o[5] = bf16_rne(b.y); o[6] = bf16_rne(b.z); o[7] = bf16_rne(b.w);
  *(u16x8*)(dst + i) = o;
}

// ---------------------------------------------------------------------------
// Phase B: LSTM recurrence. 8 blocks x 512 threads (8 waves).
// Wave (g = wid&3, qg = wid>>2) owns gate g, cols q0 = blk*64+qg*32 .. +32,
// holding W_h fragments in 128 VGPRs (bf16) for the whole kernel.
// Per step: stage h (bf16, XOR-swizzled LDS) -> MFMA P = h @ Wh^T ->
// LDS gate-combine -> elementwise c/h update -> store h to Hs[t] (global) ->
// custom 8-block barrier (monotonic counter, agent fences).
// ---------------------------------------------------------------------------
__global__ void __launch_bounds__(512, 2) lstm_mfma(
    const float* __restrict__ E,
    const float* __restrict__ Wf, const float* __restrict__ Wi,
    const float* __restrict__ Wo, const float* __restrict__ Wc,
    const float* __restrict__ Cin,
    unsigned short* __restrict__ HsM1,   // [-1..127][32][512] bf16 (slot -1 = h_init)
    float* __restrict__ outHC,
    unsigned* __restrict__ bar)
{
  __shared__ short hl[BB * HD];      // 32KB swizzled bf16 h
  __shared__ float Pl[4][BB][64];    // 32KB gate pre-activations
  __shared__ float cl[BB][64];       // 8KB cell state (persistent)

  const int tid = threadIdx.x;
  const int blk = blockIdx.x;
  const int wid = tid >> 6, lane = tid & 63;
  const int g = wid & 3, qg = wid >> 2;
  const int fr = lane & 15, ko = lane >> 4;

  unsigned short* Hs = HsM1 + BB * HD;

  // ---- one-time: weight fragments into registers (B-frag layout of 16x16x32) ----
  const float* Wg = (g == 0) ? Wf : (g == 1) ? Wi : (g == 2) ? Wo : Wc;
  short8 wreg[2][16];
  #pragma unroll
  for (int n = 0; n < 2; ++n) {
    const int q = blk * 64 + qg * 32 + n * 16 + fr;
    const float* rowp = Wg + (size_t)q * VH + V;
    #pragma unroll
    for (int kk = 0; kk < 16; ++kk) {
      const float4 lo = *(const float4*)(rowp + kk * 32 + ko * 8);
      const float4 hi = *(const float4*)(rowp + kk * 32 + ko * 8 + 4);
      short8 w;
      w[0] = (short)bf16_rne(lo.x); w[1] = (short)bf16_rne(lo.y);
      w[2] = (short)bf16_rne(lo.z); w[3] = (short)bf16_rne(lo.w);
      w[4] = (short)bf16_rne(hi.x); w[5] = (short)bf16_rne(hi.y);
      w[6] = (short)bf16_rne(hi.z); w[7] = (short)bf16_rne(hi.w);
      wreg[n][kk] = w;
    }
  }

  // ---- one-time: cell-state init (thread owns (eb, ql..ql+3)) ----
  const int e0 = tid * 4;
  const int eb = e0 >> 6, ql = e0 & 63;
  const int qglob = blk * 64 + ql;
  {
    const f32x4 c4 = *(const f32x4*)(Cin + eb * HD + qglob);
    *(f32x4*)&cl[eb][ql] = c4;
  }

  // A-frag address bases (row = m*16 + fr, swizzle = (row&7)<<4)
  int abase[2], asw[2];
  #pragma unroll
  for (int m = 0; m < 2; ++m) {
    const int r = m * 16 + fr;
    abase[m] = r * 1024;
    asw[m] = (r & 7) << 4;
  }

  for (int t = 0; t < TT; ++t) {
    if (t > 0) {
      __syncthreads();   // all Hs[t-1] stores drained (vmcnt0 before s_barrier)
      if (tid == 0) {
        __threadfence();  // release: wbl2 -> h visible at coherence point
        __hip_atomic_fetch_add(bar, 1u, __ATOMIC_RELAXED, __HIP_MEMORY_SCOPE_AGENT);
        const unsigned tgt = (unsigned)(LBLK * t);
        while (__hip_atomic_load(bar, __ATOMIC_RELAXED, __HIP_MEMORY_SCOPE_AGENT) < tgt) {}
        __threadfence();  // acquire: invalidate L1/L2 before reading peers' h
      }
      __syncthreads();
    }

    // stage h_{t-1} (32KB bf16) into LDS, XOR-swizzled via pre-swizzled source
    const char* hsrc = (const char*)(HsM1 + (size_t)t * (BB * HD));
    #pragma unroll
    for (int is = 0; is < 4; ++is) {
      const int i = is * 512 + tid;
      const int sb = (i >> 6) * 1024 + (((i & 63) * 16) ^ (((i >> 6) & 7) << 4));
      gload_lds16(hsrc + sb, (char*)hl + (size_t)(is * 512 + (tid & ~63)) * 16);
    }

    // E prefetch (independent of h; hides under staging + MFMA)
    const float* Eb = E + ((size_t)t * 4) * BB * HD;
    const f32x4 ef = *(const f32x4*)(Eb + (size_t)(0 * BB + eb) * HD + qglob);
    const f32x4 ei = *(const f32x4*)(Eb + (size_t)(1 * BB + eb) * HD + qglob);
    const f32x4 eo = *(const f32x4*)(Eb + (size_t)(2 * BB + eb) * HD + qglob);
    const f32x4 ec = *(const f32x4*)(Eb + (size_t)(3 * BB + eb) * HD + qglob);

    __syncthreads();   // h_lds ready (drains vmcnt)

    f32x4 acc[2][2];
    #pragma unroll
    for (int m = 0; m < 2; ++m)
      #pragma unroll
      for (int n = 0; n < 2; ++n)
        acc[m][n] = (f32x4){0.f, 0.f, 0.f, 0.f};

    #pragma unroll
    for (int kk = 0; kk < 16; ++kk) {
      const int off = kk * 64 + ko * 16;
      const short8 a0 = *(const short8*)((const char*)hl + abase[0] + (off ^ asw[0]));
      const short8 a1 = *(const short8*)((const char*)hl + abase[1] + (off ^ asw[1]));
      acc[0][0] = __builtin_amdgcn_mfma_f32_16x16x32_bf16(a0, wreg[0][kk], acc[0][0], 0, 0, 0);
      acc[1][0] = __builtin_amdgcn_mfma_f32_16x16x32_bf16(a1, wreg[0][kk], acc[1][0], 0, 0, 0);
      acc[0][1] = __builtin_amdgcn_mfma_f32_16x16x32_bf16(a0, wreg[1][kk], acc[0][1], 0, 0, 0);
      acc[1][1] = __builtin_amdgcn_mfma_f32_16x16x32_bf16(a1, wreg[1][kk], acc[1][1], 0, 0, 0);
    }

    // write P to LDS: C-layout row b = m*16 + ko*4 + j, col q = qg*32 + n*16 + fr
    #pragma unroll
    for (int m = 0; m < 2; ++m)
      #pragma unroll
      for (int n = 0; n < 2; ++n)
        #pragma unroll
        for (int j = 0; j < 4; ++j)
          Pl[g][m * 16 + ko * 4 + j][qg * 32 + n * 16 + fr] = acc[m][n][j];
    __syncthreads();

    // elementwise gate update: thread owns (eb, ql..ql+3)
    const f32x4 pf4 = *(const f32x4*)&Pl[0][eb][ql];
    const f32x4 pi4 = *(const f32x4*)&Pl[1][eb][ql];
    const f32x4 po4 = *(const f32x4*)&Pl[2][eb][ql];
    const f32x4 pc4 = *(const f32x4*)&Pl[3][eb][ql];
    const f32x4 cold = *(const f32x4*)&cl[eb][ql];
    f32x4 cnew, hnew;
    u16x4 hq;
    #pragma unroll
    for (int j = 0; j < 4; ++j) {
      const float fg = sigf(pf4[j] + ef[j]);
      const float ig = sigf(pi4[j] + ei[j]);
      const float og = sigf(po4[j] + eo[j]);
      const float ct = tanhf_fast(pc4[j] + ec[j]);
      const float cn = fg * cold[j] + ig * ct;
      const float hv = og * tanhf_fast(cn);
      cnew[j] = cn;
      hnew[j] = hv;
      hq[j] = bf16_rne(hv);
    }
    *(f32x4*)&cl[eb][ql] = cnew;
    *(u16x4*)(Hs + ((size_t)t * BB + eb) * HD + qglob) = hq;
    if (t == TT - 1) {
      *(f32x4*)(outHC + (size_t)eb * HD + qglob) = hnew;
      *(f32x4*)(outHC + (size_t)BB * HD + (size_t)eb * HD + qglob) = cnew;
    }
  }
}

// ---------------------------------------------------------------------------
// Phase C: Y[4096][32000] = Hs(bf16) @ Wy(bf16)^T + by.  128x128 tile, BK=64.
// ---------------------------------------------------------------------------
__global__ void __launch_bounds__(256, 1) gemm_kernel(
    const unsigned short* __restrict__ A,    // [4096][512]
    const unsigned short* __restrict__ Bw,   // [32000][512]
    const float* __restrict__ by,
    float* __restrict__ Y)
{
  __shared__ unsigned short As[128 * 64];
  __shared__ unsigned short Bs[128 * 64];
  const int tid = threadIdx.x;
  const int bidx = blockIdx.x;
  const int bm = bidx & 31, bn = bidx >> 5;
  const int row0 = bm << 7, col0 = bn << 7;
  const int wave = tid >> 6, lane = tid & 63;
  const int wr = wave >> 1, wc = wave & 1;
  const int fr = lane & 15;
  const int ko = lane >> 4;

  f32x4 acc[4][4];
  #pragma unroll
  for (int m = 0; m < 4; ++m)
    #pragma unroll
    for (int n = 0; n < 4; ++n)
      acc[m][n] = (f32x4){0.f, 0.f, 0.f, 0.f};

  for (int kt = 0; kt < 8; ++kt) {
    const int k0 = kt << 6;
    #pragma unroll
    for (int is = 0; is < 4; ++is) {
      const int id = is * 256 + tid;
      const int r = id >> 3;
      const int c = (id & 7) ^ (r & 7);
      gload_lds16(A + (size_t)(row0 + r) * 512 + k0 + c * 8,
                  &As[(is * 256 + (tid & ~63)) * 8]);
    }
    #pragma unroll
    for (int is = 0; is < 4; ++is) {
      const int id = is * 256 + tid;
      const int r = id >> 3;
      const int c = (id & 7) ^ (r & 7);
      gload_lds16(Bw + (size_t)(col0 + r) * 512 + k0 + c * 8,
                  &Bs[(is * 256 + (tid & ~63)) * 8]);
    }
    __syncthreads();
    #pragma unroll
    for (int kk = 0; kk < 2; ++kk) {
      short8 af[4], bfrag[4];
      #pragma unroll
      for (int m = 0; m < 4; ++m) {
        const int r = (wr << 6) + (m << 4) + fr;
        const int c = ((kk << 2) | ko) ^ (r & 7);
        af[m] = *(const short8*)&As[r * 64 + c * 8];
      }
      #pragma unroll
      for (int n = 0; n < 4; ++n) {
        const int r = (wc << 6) + (n << 4) + fr;
        const int c = ((kk << 2) | ko) ^ (r & 7);
        bfrag[n] = *(const short8*)&Bs[r * 64 + c * 8];
      }
      #pragma unroll
      for (int m = 0; m < 4; ++m)
        #pragma unroll
        for (int n = 0; n < 4; ++n)
          acc[m][n] = __builtin_amdgcn_mfma_f32_16x16x32_bf16(
              af[m], bfrag[n], acc[m][n], 0, 0, 0);
    }
    __syncthreads();
  }

  const int rgrp = lane >> 4;
  #pragma unroll
  for (int n = 0; n < 4; ++n) {
    const int col = col0 + (wc << 6) + (n << 4) + fr;
    const float bias = by[col];
    #pragma unroll
    for (int m = 0; m < 4; ++m) {
      const int rowb = row0 + (wr << 6) + (m << 4) + (rgrp << 2);
      #pragma unroll
      for (int j = 0; j < 4; ++j) {
        Y[(size_t)(rowb + j) * V + col] = acc[m][n][j] + bias;
      }
    }
  }
}

// ---------------------------------------------------------------------------
extern "C" void kernel_launch(void* const* d_in, const int* in_sizes, int n_in,
                              void* d_out, int out_size, void* d_ws, size_t ws_size,
                              hipStream_t stream)
{
  const int*   X  = (const int*)  d_in[0];
  const float* H  = (const float*)d_in[1];
  const float* C  = (const float*)d_in[2];
  const float* Wf = (const float*)d_in[3];
  const float* bf = (const float*)d_in[4];
  const float* Wi = (const float*)d_in[5];
  const float* bi = (const float*)d_in[6];
  const float* Wo = (const float*)d_in[7];
  const float* bo = (const float*)d_in[8];
  const float* Wc = (const float*)d_in[9];
  const float* bc = (const float*)d_in[10];
  const float* Wy = (const float*)d_in[11];
  const float* by = (const float*)d_in[12];

  float* Y = (float*)d_out;
  float* outHC = Y + (size_t)TT * BB * V;

  char* ws = (char*)d_ws;
  float* E              = (float*)ws;                               // 33,554,432 B
  unsigned short* Wyb   = (unsigned short*)(ws + 33554432);         // 32,768,000 B
  unsigned short* HsM1  = (unsigned short*)(ws + 66322432);         // 32,768 + 4,194,304 B
  unsigned short* Hs    = HsM1 + BB * HD;
  unsigned* bar         = (unsigned*)(ws + 70549504);               // 64 B

  (void)hipMemsetAsync(bar, 0, 64, stream);

  // h_init = bf16(H)  (HsM1 slot -1)
  f32_to_bf16_k<<<8, 256, 0, stream>>>(HsM1, H, (size_t)BB * HD);
  gather_kernel<<<TT * BB, 256, 0, stream>>>(E, X, Wf, bf, Wi, bi, Wo, bo, Wc, bc);
  f32_to_bf16_k<<<8000, 256, 0, stream>>>(Wyb, Wy, (size_t)V * HD);

  {
    const float* E_p = E;
    unsigned short* HsM1_p = HsM1;
    float* outHC_p = outHC;
    unsigned* bar_p = bar;
    void* args[] = {(void*)&E_p, (void*)&Wf, (void*)&Wi, (void*)&Wo, (void*)&Wc,
                    (void*)&C, (void*)&HsM1_p, (void*)&outHC_p, (void*)&bar_p};
    (void)hipLaunchCooperativeKernel((void*)lstm_mfma, dim3(LBLK), dim3(512), args, 0, stream);
  }

  gemm_kernel<<<8000, 256, 0, stream>>>(Hs, Wyb, by, Y);
}

// Round 4
// 1084.460 us; speedup vs baseline: 5.2712x; 1.0840x over previous
//
#include <hip/hip_runtime.h>
#include <hip/hip_bf16.h>

#define V  32000
#define HD 512
#define BB 32
#define TT 128
#define VH 32512   // V + HD
#define LBLK 8     // lstm blocks (weights live in these 8 CUs' registers)
#define NBLK 256   // total co-resident blocks (1 per CU)
#define GBLK (NBLK - LBLK)
#define NTILE (32 * 125)   // gemm tiles: 4096/128 x 32000/256

typedef short  short8  __attribute__((ext_vector_type(8)));
typedef unsigned short u16x8 __attribute__((ext_vector_type(8)));
typedef unsigned short u16x4 __attribute__((ext_vector_type(4)));
typedef float  f32x4   __attribute__((ext_vector_type(4)));

__device__ __forceinline__ unsigned short bf16_rne(float f) {
  unsigned u = __builtin_bit_cast(unsigned, f);
  u += 0x7FFFu + ((u >> 16) & 1u);
  return (unsigned short)(u >> 16);
}

__device__ __forceinline__ void gload_lds16(const void* g, void* l) {
  __builtin_amdgcn_global_load_lds((const __attribute__((address_space(1))) void*)g,
                                   (__attribute__((address_space(3))) void*)l, 16, 0, 0);
}

__device__ __forceinline__ float sigf(float x) {
  return 1.0f / (1.0f + __expf(-x));
}
__device__ __forceinline__ float tanhf_fast(float x) {
  return 1.0f - 2.0f / (1.0f + __expf(2.0f * x));
}

// ---------------------------------------------------------------------------
// Phase A: embedding gather. E[t][g][b][q] = W_g[q][x_tb] + bias_g[q]
// ---------------------------------------------------------------------------
__global__ void __launch_bounds__(256) gather_kernel(
    float* __restrict__ E, const int* __restrict__ X,
    const float* __restrict__ Wf, const float* __restrict__ bf,
    const float* __restrict__ Wi, const float* __restrict__ bi,
    const float* __restrict__ Wo, const float* __restrict__ bo,
    const float* __restrict__ Wc, const float* __restrict__ bc)
{
  const int bid = blockIdx.x;
  const int t = bid >> 5, b = bid & 31;
  const int x = X[b * TT + t];
  const int tid = threadIdx.x;
  #pragma unroll
  for (int i = 0; i < 8; ++i) {
    const int g = i >> 1;
    const int q = ((i & 1) << 8) + tid;
    const float* W = (g == 0) ? Wf : (g == 1) ? Wi : (g == 2) ? Wo : Wc;
    const float* bs = (g == 0) ? bf : (g == 1) ? bi : (g == 2) ? bo : bc;
    const float e = W[(size_t)q * VH + x] + bs[q];
    E[(((size_t)t * 4 + g) * 32 + b) * 512 + q] = e;
  }
}

// ---------------------------------------------------------------------------
// f32 -> bf16 bulk convert
// ---------------------------------------------------------------------------
__global__ void __launch_bounds__(256) f32_to_bf16_k(
    unsigned short* __restrict__ dst, const float* __restrict__ src, size_t n)
{
  const size_t i = ((size_t)blockIdx.x * 256 + threadIdx.x) * 8;
  if (i >= n) return;
  const float4 a = *(const float4*)(src + i);
  const float4 b = *(const float4*)(src + i + 4);
  u16x8 o;
  o[0] = bf16_rne(a.x); o[1] = bf16_rne(a.y); o[2] = bf16_rne(a.z); o[3] = bf16_rne(a.w);
  o[4] = bf16_rne(b.x); o[5] = bf16_rne(b.y); o[6] = bf16_rne(b.z); o[7] = bf16_rne(b.w);
  *(u16x8*)(dst + i) = o;
}

// ---------------------------------------------------------------------------
// Fused cooperative kernel: 256 blocks x 512 threads (1 per CU).
//   blocks 0..7    : LSTM recurrence (weights register-resident), per-step
//                    global barrier via monotonic counter `bar`; block 0
//                    publishes progress flag `bar2 = t` (steps complete).
//   blocks 8..255  : persistent GEMM workers. Y[4096][32000] =
//                    Hs(bf16) @ Wy(bf16)^T + by, 128x256 tiles (8 waves),
//                    each tile waits until its 4 t-rows of Hs are published.
// ---------------------------------------------------------------------------
__global__ void __launch_bounds__(512, 2) fused_lstm_gemm(
    const float* __restrict__ E,
    const float* __restrict__ Wf, const float* __restrict__ Wi,
    const float* __restrict__ Wo, const float* __restrict__ Wc,
    const float* __restrict__ Cin,
    unsigned short* __restrict__ HsM1,   // [-1..127][32][512] bf16
    float* __restrict__ outHC,
    unsigned* __restrict__ bar,          // barrier counter
    unsigned* __restrict__ bar2,         // progress flag (separate line)
    const unsigned short* __restrict__ Wyb,  // [32000][512] bf16
    const float* __restrict__ by,
    float* __restrict__ Y)
{
  __shared__ __align__(16) char smem[75776];

  const int tid = threadIdx.x;
  const int blkid = blockIdx.x;
  const int wid = tid >> 6, lane = tid & 63;
  const int fr = lane & 15, ko = lane >> 4;

  unsigned short* Hs = HsM1 + BB * HD;

  if (blkid < LBLK) {
    // =======================  LSTM role  =======================
    short* hl = (short*)smem;                                   // 32768 B
    float (*Pl)[BB][68] = (float(*)[BB][68])(smem + 32768);     // 34816 B
    float (*cl)[64]     = (float(*)[64])(smem + 32768 + 34816); // 8192 B

    const int blk = blkid;
    const int g = wid & 3, qg = wid >> 2;

    // ---- one-time: weight fragments into registers (B-frag of 16x16x32) ----
    const float* Wg = (g == 0) ? Wf : (g == 1) ? Wi : (g == 2) ? Wo : Wc;
    short8 wreg[2][16];
    #pragma unroll
    for (int n = 0; n < 2; ++n) {
      const int q = blk * 64 + qg * 32 + n * 16 + fr;
      const float* rowp = Wg + (size_t)q * VH + V;
      #pragma unroll
      for (int kk = 0; kk < 16; ++kk) {
        const float4 lo = *(const float4*)(rowp + kk * 32 + ko * 8);
        const float4 hi = *(const float4*)(rowp + kk * 32 + ko * 8 + 4);
        short8 w;
        w[0] = (short)bf16_rne(lo.x); w[1] = (short)bf16_rne(lo.y);
        w[2] = (short)bf16_rne(lo.z); w[3] = (short)bf16_rne(lo.w);
        w[4] = (short)bf16_rne(hi.x); w[5] = (short)bf16_rne(hi.y);
        w[6] = (short)bf16_rne(hi.z); w[7] = (short)bf16_rne(hi.w);
        wreg[n][kk] = w;
      }
    }

    // ---- cell-state init (thread owns (eb, ql..ql+3)) ----
    const int e0 = tid * 4;
    const int eb = e0 >> 6, ql = e0 & 63;
    const int qglob = blk * 64 + ql;
    {
      const f32x4 c4 = *(const f32x4*)(Cin + eb * HD + qglob);
      *(f32x4*)&cl[eb][ql] = c4;
    }

    int abase[2], asw[2];
    #pragma unroll
    for (int m = 0; m < 2; ++m) {
      const int r = m * 16 + fr;
      abase[m] = r * 1024;
      asw[m] = (r & 7) << 4;
    }

    for (int t = 0; t < TT; ++t) {
      // E loads issued BEFORE the barrier (independent of peers; latency
      // hides under the barrier spin + staging).
      const float* Eb = E + ((size_t)t * 4) * BB * HD;
      const f32x4 ef = *(const f32x4*)(Eb + (size_t)(0 * BB + eb) * HD + qglob);
      const f32x4 ei = *(const f32x4*)(Eb + (size_t)(1 * BB + eb) * HD + qglob);
      const f32x4 eo = *(const f32x4*)(Eb + (size_t)(2 * BB + eb) * HD + qglob);
      const f32x4 ec = *(const f32x4*)(Eb + (size_t)(3 * BB + eb) * HD + qglob);

      if (t > 0) {
        __syncthreads();   // all Hs[t-1] stores issued & drained
        if (tid == 0) {
          __threadfence();  // release
          __hip_atomic_fetch_add(bar, 1u, __ATOMIC_RELAXED, __HIP_MEMORY_SCOPE_AGENT);
          const unsigned tgt = (unsigned)(LBLK * t);
          while (__hip_atomic_load(bar, __ATOMIC_RELAXED, __HIP_MEMORY_SCOPE_AGENT) < tgt) {}
          __threadfence();  // acquire
          if (blk == 0)     // publish: steps 0..t-1 complete (ordered after acquire)
            __hip_atomic_store(bar2, (unsigned)t, __ATOMIC_RELAXED, __HIP_MEMORY_SCOPE_AGENT);
        }
        __syncthreads();
      }

      // stage h_{t-1} (32KB bf16) into LDS, XOR-swizzled via source
      const char* hsrc = (const char*)(HsM1 + (size_t)t * (BB * HD));
      #pragma unroll
      for (int is = 0; is < 4; ++is) {
        const int i = is * 512 + tid;
        const int sb = (i >> 6) * 1024 + (((i & 63) * 16) ^ (((i >> 6) & 7) << 4));
        gload_lds16(hsrc + sb, (char*)hl + (size_t)(is * 512 + (tid & ~63)) * 16);
      }

      __syncthreads();   // h_lds ready

      f32x4 acc[2][2];
      #pragma unroll
      for (int m = 0; m < 2; ++m)
        #pragma unroll
        for (int n = 0; n < 2; ++n)
          acc[m][n] = (f32x4){0.f, 0.f, 0.f, 0.f};

      #pragma unroll
      for (int kk = 0; kk < 16; ++kk) {
        const int off = kk * 64 + ko * 16;
        const short8 a0 = *(const short8*)((const char*)hl + abase[0] + (off ^ asw[0]));
        const short8 a1 = *(const short8*)((const char*)hl + abase[1] + (off ^ asw[1]));
        acc[0][0] = __builtin_amdgcn_mfma_f32_16x16x32_bf16(a0, wreg[0][kk], acc[0][0], 0, 0, 0);
        acc[1][0] = __builtin_amdgcn_mfma_f32_16x16x32_bf16(a1, wreg[0][kk], acc[1][0], 0, 0, 0);
        acc[0][1] = __builtin_amdgcn_mfma_f32_16x16x32_bf16(a0, wreg[1][kk], acc[0][1], 0, 0, 0);
        acc[1][1] = __builtin_amdgcn_mfma_f32_16x16x32_bf16(a1, wreg[1][kk], acc[1][1], 0, 0, 0);
      }

      #pragma unroll
      for (int m = 0; m < 2; ++m)
        #pragma unroll
        for (int n = 0; n < 2; ++n)
          #pragma unroll
          for (int j = 0; j < 4; ++j)
            Pl[g][m * 16 + ko * 4 + j][qg * 32 + n * 16 + fr] = acc[m][n][j];
      __syncthreads();

      const f32x4 pf4 = *(const f32x4*)&Pl[0][eb][ql];
      const f32x4 pi4 = *(const f32x4*)&Pl[1][eb][ql];
      const f32x4 po4 = *(const f32x4*)&Pl[2][eb][ql];
      const f32x4 pc4 = *(const f32x4*)&Pl[3][eb][ql];
      const f32x4 cold = *(const f32x4*)&cl[eb][ql];
      f32x4 cnew, hnew;
      u16x4 hq;
      #pragma unroll
      for (int j = 0; j < 4; ++j) {
        const float fg = sigf(pf4[j] + ef[j]);
        const float ig = sigf(pi4[j] + ei[j]);
        const float og = sigf(po4[j] + eo[j]);
        const float ct = tanhf_fast(pc4[j] + ec[j]);
        const float cn = fg * cold[j] + ig * ct;
        const float hv = og * tanhf_fast(cn);
        cnew[j] = cn;
        hnew[j] = hv;
        hq[j] = bf16_rne(hv);
      }
      *(f32x4*)&cl[eb][ql] = cnew;
      *(u16x4*)(Hs + ((size_t)t * BB + eb) * HD + qglob) = hq;
      if (t == TT - 1) {
        *(f32x4*)(outHC + (size_t)eb * HD + qglob) = hnew;
        *(f32x4*)(outHC + (size_t)BB * HD + (size_t)eb * HD + qglob) = cnew;
      }
    }

    // epilogue: publish final step
    __syncthreads();
    if (tid == 0) {
      __threadfence();
      __hip_atomic_fetch_add(bar, 1u, __ATOMIC_RELAXED, __HIP_MEMORY_SCOPE_AGENT);
      if (blk == 0) {
        while (__hip_atomic_load(bar, __ATOMIC_RELAXED, __HIP_MEMORY_SCOPE_AGENT) < (unsigned)(LBLK * TT)) {}
        __threadfence();
        __hip_atomic_store(bar2, (unsigned)TT, __ATOMIC_RELAXED, __HIP_MEMORY_SCOPE_AGENT);
      }
    }
  } else {
    // =======================  GEMM role  =======================
    unsigned short* As = (unsigned short*)smem;             // 128x64 = 16384 B
    unsigned short* Bs = (unsigned short*)(smem + 16384);   // 256x64 = 32768 B

    const int wr = wid >> 2, wc = wid & 3;   // 2 x 4 wave grid

    for (int tile = blkid - LBLK; tile < NTILE; tile += GBLK) {
      const int bm = tile / 125, bn = tile % 125;
      const int row0 = bm << 7, col0 = bn << 8;

      // wait until Hs rows row0..row0+127 (steps 4bm..4bm+3) are published
      if (tid == 0) {
        const unsigned need = (unsigned)(4 * bm + 4);
        while (__hip_atomic_load(bar2, __ATOMIC_RELAXED, __HIP_MEMORY_SCOPE_AGENT) < need)
          __builtin_amdgcn_s_sleep(2);
        __threadfence();  // acquire
      }
      __syncthreads();

      f32x4 acc[4][4];
      #pragma unroll
      for (int m = 0; m < 4; ++m)
        #pragma unroll
        for (int n = 0; n < 4; ++n)
          acc[m][n] = (f32x4){0.f, 0.f, 0.f, 0.f};

      for (int kt = 0; kt < 8; ++kt) {
        const int k0 = kt << 6;
        // A: 128 rows x 64 cols -> 1024 chunks of 16B, 2 per thread
        #pragma unroll
        for (int is = 0; is < 2; ++is) {
          const int id = is * 512 + tid;
          const int r = id >> 3;
          const int c = (id & 7) ^ (r & 7);
          gload_lds16(Hs + (size_t)(row0 + r) * 512 + k0 + c * 8,
                      &As[(is * 512 + (tid & ~63)) * 8]);
        }
        // B: 256 rows x 64 cols -> 2048 chunks, 4 per thread
        #pragma unroll
        for (int is = 0; is < 4; ++is) {
          const int id = is * 512 + tid;
          const int r = id >> 3;
          const int c = (id & 7) ^ (r & 7);
          gload_lds16(Wyb + (size_t)(col0 + r) * 512 + k0 + c * 8,
                      &Bs[(is * 512 + (tid & ~63)) * 8]);
        }
        __syncthreads();
        #pragma unroll
        for (int kk = 0; kk < 2; ++kk) {
          short8 af[4], bfr[4];
          #pragma unroll
          for (int m = 0; m < 4; ++m) {
            const int r = (wr << 6) + (m << 4) + fr;
            const int c = ((kk << 2) | ko) ^ (r & 7);
            af[m] = *(const short8*)&As[r * 64 + c * 8];
          }
          #pragma unroll
          for (int n = 0; n < 4; ++n) {
            const int r = (wc << 6) + (n << 4) + fr;
            const int c = ((kk << 2) | ko) ^ (r & 7);
            bfr[n] = *(const short8*)&Bs[r * 64 + c * 8];
          }
          #pragma unroll
          for (int m = 0; m < 4; ++m)
            #pragma unroll
            for (int n = 0; n < 4; ++n)
              acc[m][n] = __builtin_amdgcn_mfma_f32_16x16x32_bf16(
                  af[m], bfr[n], acc[m][n], 0, 0, 0);
        }
        __syncthreads();
      }

      const int rgrp = lane >> 4;
      #pragma unroll
      for (int n = 0; n < 4; ++n) {
        const int col = col0 + (wc << 6) + (n << 4) + fr;
        const float bias = by[col];
        #pragma unroll
        for (int m = 0; m < 4; ++m) {
          const int rowb = row0 + (wr << 6) + (m << 4) + (rgrp << 2);
          #pragma unroll
          for (int j = 0; j < 4; ++j) {
            Y[(size_t)(rowb + j) * V + col] = acc[m][n][j] + bias;
          }
        }
      }
    }
  }
}

// ---------------------------------------------------------------------------
extern "C" void kernel_launch(void* const* d_in, const int* in_sizes, int n_in,
                              void* d_out, int out_size, void* d_ws, size_t ws_size,
                              hipStream_t stream)
{
  const int*   X  = (const int*)  d_in[0];
  const float* H  = (const float*)d_in[1];
  const float* C  = (const float*)d_in[2];
  const float* Wf = (const float*)d_in[3];
  const float* bf = (const float*)d_in[4];
  const float* Wi = (const float*)d_in[5];
  const float* bi = (const float*)d_in[6];
  const float* Wo = (const float*)d_in[7];
  const float* bo = (const float*)d_in[8];
  const float* Wc = (const float*)d_in[9];
  const float* bc = (const float*)d_in[10];
  const float* Wy = (const float*)d_in[11];
  const float* by = (const float*)d_in[12];

  float* Y = (float*)d_out;
  float* outHC = Y + (size_t)TT * BB * V;

  char* ws = (char*)d_ws;
  float* E              = (float*)ws;                               // 33,554,432 B
  unsigned short* Wyb   = (unsigned short*)(ws + 33554432);         // 32,768,000 B
  unsigned short* HsM1  = (unsigned short*)(ws + 66322432);         // 32,768 + 4,194,304 B
  unsigned* bar         = (unsigned*)(ws + 70549504);               // line 0
  unsigned* bar2        = (unsigned*)(ws + 70549504 + 64);          // line 1

  (void)hipMemsetAsync(bar, 0, 128, stream);

  f32_to_bf16_k<<<8, 256, 0, stream>>>(HsM1, H, (size_t)BB * HD);
  gather_kernel<<<TT * BB, 256, 0, stream>>>(E, X, Wf, bf, Wi, bi, Wo, bo, Wc, bc);
  f32_to_bf16_k<<<8000, 256, 0, stream>>>(Wyb, Wy, (size_t)V * HD);

  {
    const float* E_p = E;
    unsigned short* HsM1_p = HsM1;
    float* outHC_p = outHC;
    unsigned* bar_p = bar;
    unsigned* bar2_p = bar2;
    const unsigned short* Wyb_p = Wyb;
    const float* by_p = by;
    float* Y_p = Y;
    void* args[] = {(void*)&E_p, (void*)&Wf, (void*)&Wi, (void*)&Wo, (void*)&Wc,
                    (void*)&C, (void*)&HsM1_p, (void*)&outHC_p, (void*)&bar_p,
                    (void*)&bar2_p, (void*)&Wyb_p, (void*)&by_p, (void*)&Y_p};
    (void)hipLaunchCooperativeKernel((void*)fused_lstm_gemm, dim3(NBLK), dim3(512), args, 0, stream);
  }
}

// Round 5
// 1048.139 us; speedup vs baseline: 5.4538x; 1.0347x over previous
//
#include <hip/hip_runtime.h>
#include <hip/hip_bf16.h>

#define V  32000
#define HD 512
#define BB 32
#define TT 128
#define VH 32512   // V + HD
#define LBLK 8     // lstm blocks (weights live in these 8 CUs' registers)
#define NBLK 256   // total co-resident blocks (1 per CU)
#define GBLK (NBLK - LBLK)
#define NTILE (32 * 125)   // gemm tiles: 4096/128 x 32000/256

typedef short  short8  __attribute__((ext_vector_type(8)));
typedef unsigned short u16x8 __attribute__((ext_vector_type(8)));
typedef unsigned short u16x4 __attribute__((ext_vector_type(4)));
typedef float  f32x4   __attribute__((ext_vector_type(4)));

__device__ __forceinline__ unsigned short bf16_rne(float f) {
  unsigned u = __builtin_bit_cast(unsigned, f);
  u += 0x7FFFu + ((u >> 16) & 1u);
  return (unsigned short)(u >> 16);
}

__device__ __forceinline__ void gload_lds16(const void* g, void* l) {
  __builtin_amdgcn_global_load_lds((const __attribute__((address_space(1))) void*)g,
                                   (__attribute__((address_space(3))) void*)l, 16, 0, 0);
}

__device__ __forceinline__ float sigf(float x) {
  return 1.0f / (1.0f + __expf(-x));
}
__device__ __forceinline__ float tanhf_fast(float x) {
  return 1.0f - 2.0f / (1.0f + __expf(2.0f * x));
}

// ---------------------------------------------------------------------------
// Fused cooperative kernel: 256 blocks x 512 threads (1 per CU).
//   blocks 0..7   : LSTM recurrence (weights register-resident). Prologue:
//                   load wreg, convert own h_init slice, wait gather done.
//                   Per-step global barrier via monotonic counter `bar`;
//                   block 0 publishes progress `bar2 = t`.
//   blocks 8..255 : prologue: block 8+t gathers E[t] (t<128); all convert
//                   Wyb slices (grid-stride); barrier on wbar; then
//                   persistent GEMM over 128x256 tiles gated by bar2.
// Y written with non-temporal stores (write-once) to keep Wyb/E L3-resident.
// ---------------------------------------------------------------------------
__global__ void __launch_bounds__(512, 2) fused_all(
    const int* __restrict__ X,
    const float* __restrict__ Hin,
    const float* __restrict__ Cin,
    const float* __restrict__ Wf, const float* __restrict__ bfp,
    const float* __restrict__ Wi, const float* __restrict__ bip,
    const float* __restrict__ Wo, const float* __restrict__ bop,
    const float* __restrict__ Wc, const float* __restrict__ bcp,
    const float* __restrict__ Wy, const float* __restrict__ by,
    float* __restrict__ E,
    unsigned short* __restrict__ HsM1,   // [-1..127][32][512] bf16
    unsigned short* __restrict__ Wyb,    // [32000][512] bf16
    float* __restrict__ outHC,
    unsigned* __restrict__ bar,          // lstm barrier counter
    unsigned* __restrict__ bar2,         // lstm progress flag
    unsigned* __restrict__ gcount,       // gather chunks done
    unsigned* __restrict__ wbar,         // Wyb-convert arrivals
    float* __restrict__ Y)
{
  __shared__ __align__(16) char smem[75776];

  const int tid = threadIdx.x;
  const int blkid = blockIdx.x;
  const int wid = tid >> 6, lane = tid & 63;
  const int fr = lane & 15, ko = lane >> 4;

  unsigned short* Hs = HsM1 + BB * HD;

  if (blkid < LBLK) {
    // =======================  LSTM role  =======================
    short* hl = (short*)smem;                                   // 32768 B
    float (*Pl)[BB][68] = (float(*)[BB][68])(smem + 32768);     // 34816 B
    float (*cl)[64]     = (float(*)[64])(smem + 32768 + 34816); // 8192 B

    const int blk = blkid;
    const int g = wid & 3, qg = wid >> 2;

    // ---- one-time: weight fragments into registers (B-frag of 16x16x32) ----
    const float* Wg = (g == 0) ? Wf : (g == 1) ? Wi : (g == 2) ? Wo : Wc;
    short8 wreg[2][16];
    #pragma unroll
    for (int n = 0; n < 2; ++n) {
      const int q = blk * 64 + qg * 32 + n * 16 + fr;
      const float* rowp = Wg + (size_t)q * VH + V;
      #pragma unroll
      for (int kk = 0; kk < 16; ++kk) {
        const float4 lo = *(const float4*)(rowp + kk * 32 + ko * 8);
        const float4 hi = *(const float4*)(rowp + kk * 32 + ko * 8 + 4);
        short8 w;
        w[0] = (short)bf16_rne(lo.x); w[1] = (short)bf16_rne(lo.y);
        w[2] = (short)bf16_rne(lo.z); w[3] = (short)bf16_rne(lo.w);
        w[4] = (short)bf16_rne(hi.x); w[5] = (short)bf16_rne(hi.y);
        w[6] = (short)bf16_rne(hi.z); w[7] = (short)bf16_rne(hi.w);
        wreg[n][kk] = w;
      }
    }

    // ---- cell-state init + h_init bf16 conversion for own q-slice ----
    const int e0 = tid * 4;
    const int eb = e0 >> 6, ql = e0 & 63;
    const int qglob = blk * 64 + ql;
    {
      const f32x4 c4 = *(const f32x4*)(Cin + eb * HD + qglob);
      *(f32x4*)&cl[eb][ql] = c4;
      const f32x4 h4 = *(const f32x4*)(Hin + eb * HD + qglob);
      u16x4 hq;
      #pragma unroll
      for (int j = 0; j < 4; ++j) hq[j] = bf16_rne(h4[j]);
      *(u16x4*)(HsM1 + (size_t)eb * HD + qglob) = hq;
    }
    __syncthreads();

    // ---- prologue barrier: own h_init written + all E gathered ----
    if (tid == 0) {
      __threadfence();
      __hip_atomic_fetch_add(bar, 1u, __ATOMIC_RELAXED, __HIP_MEMORY_SCOPE_AGENT);
      while (__hip_atomic_load(bar, __ATOMIC_RELAXED, __HIP_MEMORY_SCOPE_AGENT) < (unsigned)LBLK ||
             __hip_atomic_load(gcount, __ATOMIC_RELAXED, __HIP_MEMORY_SCOPE_AGENT) < (unsigned)TT) {}
      __threadfence();
    }
    __syncthreads();

    int abase[2], asw[2];
    #pragma unroll
    for (int m = 0; m < 2; ++m) {
      const int r = m * 16 + fr;
      abase[m] = r * 1024;
      asw[m] = (r & 7) << 4;
    }

    for (int t = 0; t < TT; ++t) {
      // E loads issued BEFORE the barrier (latency hides under spin/staging)
      const float* Eb = E + ((size_t)t * 4) * BB * HD;
      const f32x4 ef = *(const f32x4*)(Eb + (size_t)(0 * BB + eb) * HD + qglob);
      const f32x4 ei = *(const f32x4*)(Eb + (size_t)(1 * BB + eb) * HD + qglob);
      const f32x4 eo = *(const f32x4*)(Eb + (size_t)(2 * BB + eb) * HD + qglob);
      const f32x4 ec = *(const f32x4*)(Eb + (size_t)(3 * BB + eb) * HD + qglob);

      if (t > 0) {
        __syncthreads();   // all Hs[t-1] stores issued & drained
        if (tid == 0) {
          __threadfence();  // release
          __hip_atomic_fetch_add(bar, 1u, __ATOMIC_RELAXED, __HIP_MEMORY_SCOPE_AGENT);
          const unsigned tgt = (unsigned)(LBLK * (t + 1));
          while (__hip_atomic_load(bar, __ATOMIC_RELAXED, __HIP_MEMORY_SCOPE_AGENT) < tgt) {}
          __threadfence();  // acquire
          if (blk == 0)
            __hip_atomic_store(bar2, (unsigned)t, __ATOMIC_RELAXED, __HIP_MEMORY_SCOPE_AGENT);
        }
        __syncthreads();
      }

      // stage h_{t-1} (32KB bf16) into LDS, XOR-swizzled via source
      const char* hsrc = (const char*)(HsM1 + (size_t)t * (BB * HD));
      #pragma unroll
      for (int is = 0; is < 4; ++is) {
        const int i = is * 512 + tid;
        const int sb = (i >> 6) * 1024 + (((i & 63) * 16) ^ (((i >> 6) & 7) << 4));
        gload_lds16(hsrc + sb, (char*)hl + (size_t)(is * 512 + (tid & ~63)) * 16);
      }

      __syncthreads();   // h_lds ready

      f32x4 acc[2][2];
      #pragma unroll
      for (int m = 0; m < 2; ++m)
        #pragma unroll
        for (int n = 0; n < 2; ++n)
          acc[m][n] = (f32x4){0.f, 0.f, 0.f, 0.f};

      #pragma unroll
      for (int kk = 0; kk < 16; ++kk) {
        const int off = kk * 64 + ko * 16;
        const short8 a0 = *(const short8*)((const char*)hl + abase[0] + (off ^ asw[0]));
        const short8 a1 = *(const short8*)((const char*)hl + abase[1] + (off ^ asw[1]));
        acc[0][0] = __builtin_amdgcn_mfma_f32_16x16x32_bf16(a0, wreg[0][kk], acc[0][0], 0, 0, 0);
        acc[1][0] = __builtin_amdgcn_mfma_f32_16x16x32_bf16(a1, wreg[0][kk], acc[1][0], 0, 0, 0);
        acc[0][1] = __builtin_amdgcn_mfma_f32_16x16x32_bf16(a0, wreg[1][kk], acc[0][1], 0, 0, 0);
        acc[1][1] = __builtin_amdgcn_mfma_f32_16x16x32_bf16(a1, wreg[1][kk], acc[1][1], 0, 0, 0);
      }

      #pragma unroll
      for (int m = 0; m < 2; ++m)
        #pragma unroll
        for (int n = 0; n < 2; ++n)
          #pragma unroll
          for (int j = 0; j < 4; ++j)
            Pl[g][m * 16 + ko * 4 + j][qg * 32 + n * 16 + fr] = acc[m][n][j];
      __syncthreads();

      const f32x4 pf4 = *(const f32x4*)&Pl[0][eb][ql];
      const f32x4 pi4 = *(const f32x4*)&Pl[1][eb][ql];
      const f32x4 po4 = *(const f32x4*)&Pl[2][eb][ql];
      const f32x4 pc4 = *(const f32x4*)&Pl[3][eb][ql];
      const f32x4 cold = *(const f32x4*)&cl[eb][ql];
      f32x4 cnew, hnew;
      u16x4 hq;
      #pragma unroll
      for (int j = 0; j < 4; ++j) {
        const float fg = sigf(pf4[j] + ef[j]);
        const float ig = sigf(pi4[j] + ei[j]);
        const float og = sigf(po4[j] + eo[j]);
        const float ct = tanhf_fast(pc4[j] + ec[j]);
        const float cn = fg * cold[j] + ig * ct;
        const float hv = og * tanhf_fast(cn);
        cnew[j] = cn;
        hnew[j] = hv;
        hq[j] = bf16_rne(hv);
      }
      *(f32x4*)&cl[eb][ql] = cnew;
      *(u16x4*)(Hs + ((size_t)t * BB + eb) * HD + qglob) = hq;
      if (t == TT - 1) {
        *(f32x4*)(outHC + (size_t)eb * HD + qglob) = hnew;
        *(f32x4*)(outHC + (size_t)BB * HD + (size_t)eb * HD + qglob) = cnew;
      }
    }

    // epilogue: publish final step
    __syncthreads();
    if (tid == 0) {
      __threadfence();
      __hip_atomic_fetch_add(bar, 1u, __ATOMIC_RELAXED, __HIP_MEMORY_SCOPE_AGENT);
      if (blk == 0) {
        while (__hip_atomic_load(bar, __ATOMIC_RELAXED, __HIP_MEMORY_SCOPE_AGENT) < (unsigned)(LBLK * (TT + 1))) {}
        __threadfence();
        __hip_atomic_store(bar2, (unsigned)TT, __ATOMIC_RELAXED, __HIP_MEMORY_SCOPE_AGENT);
      }
    }
  } else {
    // =======================  GEMM role  =======================
    unsigned short* As = (unsigned short*)smem;             // 128x64 = 16384 B
    unsigned short* Bs = (unsigned short*)(smem + 16384);   // 256x64 = 32768 B
    int* xs            = (int*)(smem + 49152);              // 128 B

    // ---- prologue 1: gather E[t] for chunk t = blkid - LBLK (t < TT) ----
    const int tch = blkid - LBLK;
    if (tch < TT) {
      if (tid < BB) xs[tid] = X[tid * TT + tch];
      __syncthreads();
      const int q = tid;
      float* Erow = E + ((size_t)tch * 4) * BB * HD;
      #pragma unroll
      for (int g = 0; g < 4; ++g) {
        const float* W = (g == 0) ? Wf : (g == 1) ? Wi : (g == 2) ? Wo : Wc;
        const float* bsrc = (g == 0) ? bfp : (g == 1) ? bip : (g == 2) ? bop : bcp;
        const float bias = bsrc[q];
        const float* wq = W + (size_t)q * VH;
        #pragma unroll 4
        for (int b = 0; b < BB; ++b) {
          const float v = __builtin_nontemporal_load(wq + xs[b]);
          Erow[(size_t)(g * BB + b) * HD + q] = v + bias;
        }
      }
      __syncthreads();
      if (tid == 0) {
        __threadfence();  // release gathered E
        __hip_atomic_fetch_add(gcount, 1u, __ATOMIC_RELAXED, __HIP_MEMORY_SCOPE_AGENT);
      }
    }

    // ---- prologue 2: convert Wy -> Wyb (grid-stride over GEMM blocks) ----
    {
      const size_t n = (size_t)V * HD;
      for (size_t i = ((size_t)(blkid - LBLK) * 512 + tid) * 8; i < n;
           i += (size_t)GBLK * 512 * 8) {
        const f32x4 a = __builtin_nontemporal_load((const f32x4*)(Wy + i));
        const f32x4 b = __builtin_nontemporal_load((const f32x4*)(Wy + i + 4));
        u16x8 o;
        o[0] = bf16_rne(a[0]); o[1] = bf16_rne(a[1]); o[2] = bf16_rne(a[2]); o[3] = bf16_rne(a[3]);
        o[4] = bf16_rne(b[0]); o[5] = bf16_rne(b[1]); o[6] = bf16_rne(b[2]); o[7] = bf16_rne(b[3]);
        *(u16x8*)(Wyb + i) = o;
      }
      __syncthreads();
      if (tid == 0) {
        __threadfence();  // release Wyb
        __hip_atomic_fetch_add(wbar, 1u, __ATOMIC_RELAXED, __HIP_MEMORY_SCOPE_AGENT);
        while (__hip_atomic_load(wbar, __ATOMIC_RELAXED, __HIP_MEMORY_SCOPE_AGENT) < (unsigned)GBLK)
          __builtin_amdgcn_s_sleep(2);
        __threadfence();  // acquire full Wyb
      }
      __syncthreads();
    }

    const int wr = wid >> 2, wc = wid & 3;   // 2 x 4 wave grid

    for (int tile = blkid - LBLK; tile < NTILE; tile += GBLK) {
      const int bm = tile / 125, bn = tile % 125;
      const int row0 = bm << 7, col0 = bn << 8;

      // wait until Hs rows row0..row0+127 (steps 4bm..4bm+3) are published
      if (tid == 0) {
        const unsigned need = (unsigned)(4 * bm + 4);
        while (__hip_atomic_load(bar2, __ATOMIC_RELAXED, __HIP_MEMORY_SCOPE_AGENT) < need)
          __builtin_amdgcn_s_sleep(2);
        __threadfence();  // acquire
      }
      __syncthreads();

      f32x4 acc[4][4];
      #pragma unroll
      for (int m = 0; m < 4; ++m)
        #pragma unroll
        for (int n = 0; n < 4; ++n)
          acc[m][n] = (f32x4){0.f, 0.f, 0.f, 0.f};

      for (int kt = 0; kt < 8; ++kt) {
        const int k0 = kt << 6;
        #pragma unroll
        for (int is = 0; is < 2; ++is) {
          const int id = is * 512 + tid;
          const int r = id >> 3;
          const int c = (id & 7) ^ (r & 7);
          gload_lds16(Hs + (size_t)(row0 + r) * 512 + k0 + c * 8,
                      &As[(is * 512 + (tid & ~63)) * 8]);
        }
        #pragma unroll
        for (int is = 0; is < 4; ++is) {
          const int id = is * 512 + tid;
          const int r = id >> 3;
          const int c = (id & 7) ^ (r & 7);
          gload_lds16(Wyb + (size_t)(col0 + r) * 512 + k0 + c * 8,
                      &Bs[(is * 512 + (tid & ~63)) * 8]);
        }
        __syncthreads();
        #pragma unroll
        for (int kk = 0; kk < 2; ++kk) {
          short8 af[4], bfr[4];
          #pragma unroll
          for (int m = 0; m < 4; ++m) {
            const int r = (wr << 6) + (m << 4) + fr;
            const int c = ((kk << 2) | ko) ^ (r & 7);
            af[m] = *(const short8*)&As[r * 64 + c * 8];
          }
          #pragma unroll
          for (int n = 0; n < 4; ++n) {
            const int r = (wc << 6) + (n << 4) + fr;
            const int c = ((kk << 2) | ko) ^ (r & 7);
            bfr[n] = *(const short8*)&Bs[r * 64 + c * 8];
          }
          #pragma unroll
          for (int m = 0; m < 4; ++m)
            #pragma unroll
            for (int n = 0; n < 4; ++n)
              acc[m][n] = __builtin_amdgcn_mfma_f32_16x16x32_bf16(
                  af[m], bfr[n], acc[m][n], 0, 0, 0);
        }
        __syncthreads();
      }

      const int rgrp = lane >> 4;
      #pragma unroll
      for (int n = 0; n < 4; ++n) {
        const int col = col0 + (wc << 6) + (n << 4) + fr;
        const float bias = by[col];
        #pragma unroll
        for (int m = 0; m < 4; ++m) {
          const int rowb = row0 + (wr << 6) + (m << 4) + (rgrp << 2);
          #pragma unroll
          for (int j = 0; j < 4; ++j) {
            __builtin_nontemporal_store(acc[m][n][j] + bias,
                                        &Y[(size_t)(rowb + j) * V + col]);
          }
        }
      }
    }
  }
}

// ---------------------------------------------------------------------------
extern "C" void kernel_launch(void* const* d_in, const int* in_sizes, int n_in,
                              void* d_out, int out_size, void* d_ws, size_t ws_size,
                              hipStream_t stream)
{
  const int*   X  = (const int*)  d_in[0];
  const float* H  = (const float*)d_in[1];
  const float* C  = (const float*)d_in[2];
  const float* Wf = (const float*)d_in[3];
  const float* bf = (const float*)d_in[4];
  const float* Wi = (const float*)d_in[5];
  const float* bi = (const float*)d_in[6];
  const float* Wo = (const float*)d_in[7];
  const float* bo = (const float*)d_in[8];
  const float* Wc = (const float*)d_in[9];
  const float* bc = (const float*)d_in[10];
  const float* Wy = (const float*)d_in[11];
  const float* by = (const float*)d_in[12];

  float* Y = (float*)d_out;
  float* outHC = Y + (size_t)TT * BB * V;

  char* ws = (char*)d_ws;
  float* E              = (float*)ws;                               // 33,554,432 B
  unsigned short* Wyb   = (unsigned short*)(ws + 33554432);         // 32,768,000 B
  unsigned short* HsM1  = (unsigned short*)(ws + 66322432);         // 32,768 + 4,194,304 B
  unsigned* bar         = (unsigned*)(ws + 70549504);               // line 0
  unsigned* bar2        = (unsigned*)(ws + 70549504 + 64);          // line 1
  unsigned* gcount      = (unsigned*)(ws + 70549504 + 128);         // line 2
  unsigned* wbar        = (unsigned*)(ws + 70549504 + 192);         // line 3

  (void)hipMemsetAsync(bar, 0, 256, stream);

  {
    const int* X_p = X;
    const float *H_p = H, *C_p = C;
    const float *Wf_p = Wf, *bf_p = bf, *Wi_p = Wi, *bi_p = bi;
    const float *Wo_p = Wo, *bo_p = bo, *Wc_p = Wc, *bc_p = bc;
    const float *Wy_p = Wy, *by_p = by;
    float* E_p = E;
    unsigned short* HsM1_p = HsM1;
    unsigned short* Wyb_p = Wyb;
    float* outHC_p = outHC;
    unsigned *bar_p = bar, *bar2_p = bar2, *gcount_p = gcount, *wbar_p = wbar;
    float* Y_p = Y;
    void* args[] = {(void*)&X_p, (void*)&H_p, (void*)&C_p,
                    (void*)&Wf_p, (void*)&bf_p, (void*)&Wi_p, (void*)&bi_p,
                    (void*)&Wo_p, (void*)&bo_p, (void*)&Wc_p, (void*)&bc_p,
                    (void*)&Wy_p, (void*)&by_p,
                    (void*)&E_p, (void*)&HsM1_p, (void*)&Wyb_p, (void*)&outHC_p,
                    (void*)&bar_p, (void*)&bar2_p, (void*)&gcount_p, (void*)&wbar_p,
                    (void*)&Y_p};
    (void)hipLaunchCooperativeKernel((void*)fused_all, dim3(NBLK), dim3(512), args, 0, stream);
  }
}